// Round 10
// baseline (182.416 us; speedup 1.0000x reference)
//
#include <hip/hip_runtime.h>
#include <math.h>

#define T_ 4096
#define NROWS 16384            // B*T

typedef __attribute__((ext_vector_type(8))) short short8;   // 8 bf16
typedef __attribute__((ext_vector_type(4))) short short4v;  // 4 bf16
typedef __attribute__((ext_vector_type(4))) float float4v;
typedef __attribute__((ext_vector_type(2))) unsigned uint2v;

#define MFMA(a, b, c) __builtin_amdgcn_mfma_f32_16x16x32_bf16((a), (b), (c), 0, 0, 0)

#if defined(__has_builtin)
#if __has_builtin(__builtin_amdgcn_exp2f)
#define EXP2(x) __builtin_amdgcn_exp2f(x)
#else
#define EXP2(x) exp2f(x)
#endif
#else
#define EXP2(x) exp2f(x)
#endif

#define SCALE_Q 0.18033688011112042f   // 0.125 * log2(e), folded into Q

__device__ __forceinline__ short f2bf(float f) {
    unsigned u = __builtin_bit_cast(unsigned, f);
    u += 0x7fffu + ((u >> 16) & 1u);          // RNE truncate to bf16
    return (short)(u >> 16);
}
__device__ __forceinline__ float bf2f(short s) {
    return __builtin_bit_cast(float, ((unsigned)(unsigned short)s) << 16);
}
__device__ __forceinline__ unsigned pack_bf2(float a, float b) {
    unsigned ua = __builtin_bit_cast(unsigned, a);
    unsigned ub = __builtin_bit_cast(unsigned, b);
    ua += 0x7fffu + ((ua >> 16) & 1u);
    ub += 0x7fffu + ((ub >> 16) & 1u);
    return (ua >> 16) | (ub & 0xffff0000u);
}

// ---------------------------------------------------------------------------
// Kernel 0: weights fp32 (C x 64) -> Wt2 in FRAGMENT-MAJOR layout (round 8).
// ---------------------------------------------------------------------------
__global__ void wprep_kernel(const float* __restrict__ Wq,
                             const float* __restrict__ Wk,
                             const float* __restrict__ Wv,
                             short* __restrict__ Wt2)
{
    const int ck = blockIdx.x;            // 0..31 (k chunk of 32)
    const int t = threadIdx.x;
    const int sub = t >> 6, lane = t & 63;
    const int ln = lane & 15, quad = lane >> 4;
#pragma unroll
    for (int jj = 0; jj < 3; ++jj) {
        const int nt = sub * 3 + jj;      // 0..11
        const float* W = (nt < 4) ? Wq : (nt < 8) ? Wk : Wv;
        const int col = (nt & 3) * 16 + ln;
        short8 o;
#pragma unroll
        for (int j = 0; j < 8; ++j)
            o[j] = f2bf(W[(size_t)(ck * 32 + quad * 8 + j) * 64 + col]);
        *(short8*)(Wt2 + ((size_t)(ck * 12 + nt) * 64 + lane) * 8) = o;
    }
}

// ---------------------------------------------------------------------------
// Kernel 1: MFMA QKV projection + fused RoPE, 4-way split-K, 32 rows/block.
// Phase A (NEW): wave w loads its k-slice of all 32 rows as 32 COALESCED
// 1 KB float4 bursts (lane = 4 consecutive floats of one row), converts to
// bf16 and writes a wave-private frag-major LDS tile with XOR swizzle
// (granule ^ (row&7)) -> bank-optimal b64 writes and b128 frag reads.
// No staging barrier (wave-private tile, in-wave DS ordering).
// Phase B: frag-major W (L2, coalesced) + LDS A-frags -> 24 MFMA/iter.
// Merge buffer OVERLAYS each wave's own consumed x-tile (12 KB of 16 KB),
// so LDS = 64 KB + KT ~4.5 KB -> still 2 blocks/CU.
// Epilogue unchanged: Q row-major scaled, K -> A-frag-major via KT tile,
// V -> B-frag-major.
// ---------------------------------------------------------------------------
__global__ __launch_bounds__(256, 2) void qkv_kernel(
    const float* __restrict__ x, const float* __restrict__ cosp,
    const float* __restrict__ sinp, const short* __restrict__ Wt2,
    short* __restrict__ Qb, short* __restrict__ Ks, short* __restrict__ Vs)
{
    __shared__ __align__(16) short U[32768];   // 64 KB: x-tiles, then MB overlay
    __shared__ short KT[32][72];               // K transpose tile (+pad), 4.5 KB

    const int t = threadIdx.x, w = t >> 6, lane = t & 63;
    const int ln = lane & 15, quad = lane >> 4;
    const int rb = blockIdx.x * 32;
    const int k0 = w * 256;

    short* tile = U + w * 8192;                // wave-private 16 KB (8192 shorts)
    const short* wp2 = Wt2 + ((size_t)(w * 8) * 12 * 64 + lane) * 8;

    // ---- Phase A: coalesced x row-loads -> bf16 -> swizzled frag-major LDS ----
    {
        const int gr  = lane >> 1;             // 16B granule 0..31 within row slice
        const int hof = (lane & 1) * 4;        // half-granule offset (shorts)
#pragma unroll
        for (int half = 0; half < 2; ++half) {
            float4 xf[16];
#pragma unroll
            for (int r = 0; r < 16; ++r)
                xf[r] = *(const float4*)(x + (size_t)(rb + half * 16 + r) * 1024
                                           + k0 + lane * 4);
#pragma unroll
            for (int r = 0; r < 16; ++r) {
                const int row = half * 16 + r;
                const int grs = gr ^ (row & 7);        // XOR swizzle
                short4v pv;
                pv[0] = f2bf(xf[r].x); pv[1] = f2bf(xf[r].y);
                pv[2] = f2bf(xf[r].z); pv[3] = f2bf(xf[r].w);
                *(short4v*)(tile + row * 256 + grs * 8 + hof) = pv;
            }
        }
    }

    float4v acc[2][12];
#pragma unroll
    for (int af = 0; af < 2; ++af)
#pragma unroll
        for (int i = 0; i < 12; ++i) acc[af][i] = (float4v){0.f, 0.f, 0.f, 0.f};

    // ---- Phase B: W (frag-major, coalesced L2) + LDS A-frags -> MFMA ----
    const int key = ln & 7;
#pragma unroll
    for (int it = 0; it < 8; ++it) {
        const int gswz = ((it * 4 + quad) ^ key) * 8;
        const short8 a0 = *(const short8*)(tile + ln * 256 + gswz);
        const short8 a1 = *(const short8*)(tile + 4096 + ln * 256 + gswz);
        short8 bf[12];
#pragma unroll
        for (int nt = 0; nt < 12; ++nt)
            bf[nt] = *(const short8*)(wp2 + (size_t)(it * 12 + nt) * 512);
#pragma unroll
        for (int nt = 0; nt < 12; ++nt) {
            acc[0][nt] = MFMA(a0, bf[nt], acc[0][nt]);
            acc[1][nt] = MFMA(a1, bf[nt], acc[1][nt]);
        }
    }

    // partials -> LDS (bf16), overlaying this wave's own consumed x-tile
    short4v* MBw = (short4v*)tile;             // [af][nt][lane] = 12 KB
#pragma unroll
    for (int af = 0; af < 2; ++af)
#pragma unroll
        for (int nt = 0; nt < 12; ++nt) {
            short4v pv;
#pragma unroll
            for (int reg = 0; reg < 4; ++reg) pv[reg] = f2bf(acc[af][nt][reg]);
            MBw[(af * 12 + nt) * 64 + lane] = pv;
        }
    __syncthreads();

    // merge + epilogue: wave w handles nt = 3w..3w+2, both row groups
    const int b  = rb >> 12;
    const int kt = (rb & (T_ - 1)) >> 6;
#pragma unroll
    for (int af = 0; af < 2; ++af) {
        const int rb16 = rb + af * 16;
#pragma unroll
        for (int j = 0; j < 3; ++j) {
            const int nt = w * 3 + j;
            float m[4] = {0.f, 0.f, 0.f, 0.f};
#pragma unroll
            for (int p = 0; p < 4; ++p) {
                const short4v pv =
                    ((const short4v*)(U + p * 8192))[(af * 12 + nt) * 64 + lane];
#pragma unroll
                for (int reg = 0; reg < 4; ++reg) m[reg] += bf2f(pv[reg]);
            }
            if (nt < 4) {                          // Q + RoPE (scaled), row-major
                const int col = nt * 16 + ln;
#pragma unroll
                for (int reg = 0; reg < 4; ++reg) {
                    const int g  = rb16 + quad * 4 + reg;
                    const int tp = g & (T_ - 1);
                    const float cv = cosp[(size_t)tp * 64 + col];
                    const float sv = sinp[(size_t)tp * 64 + col];
                    const float v  = m[reg];
                    const float vp = __shfl_xor(v, 1, 64);
                    const float rot = (ln & 1) ? vp : -vp;
                    Qb[(size_t)g * 64 + col] = f2bf(fmaf(v, cv, rot * sv) * SCALE_Q);
                }
            } else if (nt < 8) {                   // K + RoPE -> LDS transpose tile
                const int col = (nt & 3) * 16 + ln;
#pragma unroll
                for (int reg = 0; reg < 4; ++reg) {
                    const int g  = rb16 + quad * 4 + reg;
                    const int tp = g & (T_ - 1);
                    const float cv = cosp[(size_t)tp * 64 + col];
                    const float sv = sinp[(size_t)tp * 64 + col];
                    const float v  = m[reg];
                    const float vp = __shfl_xor(v, 1, 64);
                    const float rot = (ln & 1) ? vp : -vp;
                    KT[af * 16 + quad * 4 + reg][col] = f2bf(fmaf(v, cv, rot * sv));
                }
            } else {                               // V -> swizzled B-frag layout
                const int vnt = nt - 8;
                const int rowgrp = (rb16 >> 4) & 3;
                const int hh = rowgrp >> 1;
                const int qp = (rowgrp & 1) * 2 + (quad >> 1);
                const int jb = (quad & 1) * 4;
                short4v pv;
#pragma unroll
                for (int reg = 0; reg < 4; ++reg) pv[reg] = f2bf(m[reg]);
                const size_t addr =
                    ((((size_t)(b * 64 + kt) * 4 + vnt) * 2 + hh) * 64 + qp * 16 + ln) * 8 + jb;
                *(short4v*)(Vs + addr) = pv;
            }
        }
    }
    __syncthreads();   // KT complete

    // K frag-major store: wave w handles (af2 = w>>1, h2 = w&1); coalesced 1 KB
    {
        const int af2 = w >> 1, h2 = w & 1;
        const int st2 = ((rb >> 4) & 3) + af2;     // 16-row group within 64-tile
        const short8 kfrag = *(const short8*)(&KT[af2 * 16 + ln][h2 * 32 + quad * 8]);
        *(short8*)(Ks + (((size_t)(b * 64 + kt) * 8 + st2 * 2 + h2) * 64 + lane) * 8) = kfrag;
    }
}

// ---------------------------------------------------------------------------
// Kernel 2: MFMA flash attention, 4-way split-K, NO max tracking, K+V
// register double-buffered, work-balanced pairing, frag-major K and V
// (all loads lane-contiguous). Unchanged from round 9 — verified.
// ---------------------------------------------------------------------------
#define LOADK(kf, ktv)                                                         \
    {   const short* _kb = Ksp + (size_t)(ktv) * 4096 + lane * 8;              \
        _Pragma("unroll")                                                      \
        for (int u = 0; u < 8; ++u) kf[u] = *(const short8*)(_kb + u * 512); }

#define LOADV(vf, ktv)                                                         \
    {   const short* _vb = Vp + (size_t)(ktv) * 4096 + lane * 8;               \
        _Pragma("unroll")                                                      \
        for (int u = 0; u < 8; ++u) vf[u] = *(const short8*)(_vb + u * 512); }

#define STEP(ktv, kf, vf, masked)                                              \
    {   float4v s[4];                                                          \
        _Pragma("unroll")                                                      \
        for (int st = 0; st < 4; ++st) {                                       \
            s[st] = (float4v){0.f, 0.f, 0.f, 0.f};                             \
            s[st] = MFMA(kf[st * 2],     qb0, s[st]);   /* S^T = K*Q^T */      \
            s[st] = MFMA(kf[st * 2 + 1], qb1, s[st]);                          \
        }                                                                      \
        if (masked) {                                                          \
            _Pragma("unroll")                                                  \
            for (int st = 0; st < 4; ++st)                                     \
                _Pragma("unroll")                                              \
                for (int r = 0; r < 4; ++r)                                    \
                    if ((ktv) * 64 + st * 16 + quad * 4 + r > qr0 + ln)        \
                        s[st][r] = -__builtin_inff();                          \
        }                                                                      \
        _Pragma("unroll")                                                      \
        for (int st = 0; st < 4; ++st)                                         \
            _Pragma("unroll")                                                  \
            for (int r = 0; r < 4; ++r) {                                      \
                const float p = EXP2(s[st][r]);                                \
                s[st][r] = p; lsum += p;                                       \
            }                                                                  \
        _Pragma("unroll")                                                      \
        for (int st = 0; st < 4; ++st) {                                       \
            uint2v pk;                                                         \
            pk[0] = pack_bf2(s[st][0], s[st][1]);                              \
            pk[1] = pack_bf2(s[st][2], s[st][3]);                              \
            *(uint2v*)(pw + ln * 104 + st * 16 + quad * 4) = pk;               \
        }                                                                      \
        const short8 ap0 = *(const short8*)(pw + ln * 104 + quad * 8);         \
        const short8 ap1 = *(const short8*)(pw + ln * 104 + quad * 8 + 32);    \
        _Pragma("unroll")                                                      \
        for (int vn = 0; vn < 4; ++vn) {                                       \
            o[vn] = MFMA(ap0, vf[vn * 2],     o[vn]);                          \
            o[vn] = MFMA(ap1, vf[vn * 2 + 1], o[vn]);                          \
        }                                                                      \
    }

__global__ __launch_bounds__(256, 2) void attn_kernel(
    const short* __restrict__ Qb, const short* __restrict__ Ks,
    const short* __restrict__ Vs, float* __restrict__ out)
{
    __shared__ __align__(16) short PLs[4][16 * 104];  // per-wave P tile
    __shared__ float OL[4][16][68];
    __shared__ float SL[4][16];

    const int t = threadIdx.x, w = t >> 6, lane = t & 63;
    const int ln = lane & 15, quad = lane >> 4;
    const int b = blockIdx.y;
    const short* Qp  = Qb + (size_t)b * T_ * 64;
    const short* Ksp = Ks + (size_t)b * T_ * 64;
    const short* Vp  = Vs + (size_t)b * T_ * 64;
    short* pw = PLs[w];

    for (int job = 0; job < 2; ++job) {
        const int qi = job ? 255 - (int)blockIdx.x : (int)blockIdx.x;
        const int qr0 = qi * 16;

        // Q as B-operand (pre-scaled by 0.125*log2e in qkv epilogue)
        const short8 qb0 = *(const short8*)(Qp + (size_t)(qr0 + ln) * 64 + quad * 8);
        const short8 qb1 = *(const short8*)(Qp + (size_t)(qr0 + ln) * 64 + quad * 8 + 32);

        float lsum = 0.f;
        float4v o[4];
#pragma unroll
        for (int i = 0; i < 4; ++i) o[i] = (float4v){0.f, 0.f, 0.f, 0.f};

        const int ktend = qi >> 2;
        short8 k0f[8], k1f[8], v0f[8], v1f[8];

        int kt = w;
        if (kt <= ktend) {
            LOADK(k0f, kt)
            LOADV(v0f, kt)
            while (true) {
                {
                    const bool more = (kt + 4) <= ktend;
                    if (more) { LOADK(k1f, kt + 4) LOADV(v1f, kt + 4) }
                    STEP(kt, k0f, v0f, kt == ktend)
                    kt += 4;
                    if (!more) break;
                }
                {
                    const bool more = (kt + 4) <= ktend;
                    if (more) { LOADK(k0f, kt + 4) LOADV(v0f, kt + 4) }
                    STEP(kt, k1f, v1f, kt == ktend)
                    kt += 4;
                    if (!more) break;
                }
            }
        }

        // deferred l reduction over quad (2 shfls total)
        lsum += __shfl_xor(lsum, 16, 64);
        lsum += __shfl_xor(lsum, 32, 64);

        // partials -> LDS (plain, no rescale needed)
#pragma unroll
        for (int vn = 0; vn < 4; ++vn)
#pragma unroll
            for (int r = 0; r < 4; ++r)
                OL[w][quad * 4 + r][vn * 16 + ln] = o[vn][r];
        if (quad == 0) SL[w][ln] = lsum;
        __syncthreads();

        // merge = plain sum: this wave stores rows w*4+quad (cols ln*4..+3)
        const int row = w * 4 + quad;
        const float lstar = SL[0][row] + SL[1][row] + SL[2][row] + SL[3][row];
        float ox = 0.f, oy = 0.f, oz = 0.f, ow = 0.f;
#pragma unroll
        for (int p = 0; p < 4; ++p) {
            const float4 ov = *(const float4*)&OL[p][row][ln * 4];
            ox += ov.x; oy += ov.y; oz += ov.z; ow += ov.w;
        }
        const float inv = 1.f / lstar;
        float4 res; res.x = ox * inv; res.y = oy * inv; res.z = oz * inv; res.w = ow * inv;
        *(float4*)(out + ((size_t)b * T_ + qr0 + row) * 64 + ln * 4) = res;
        __syncthreads();   // LDS buffers reused by next job
    }
}

extern "C" void kernel_launch(void* const* d_in, const int* in_sizes, int n_in,
                              void* d_out, int out_size, void* d_ws, size_t ws_size,
                              hipStream_t stream)
{
    const float* x    = (const float*)d_in[0];
    const float* cosp = (const float*)d_in[1];
    const float* sinp = (const float*)d_in[2];
    // d_in[3] = tril: unused (causality structural)
    const float* Wq   = (const float*)d_in[4];
    const float* Wk   = (const float*)d_in[5];
    const float* Wv   = (const float*)d_in[6];
    float* out = (float*)d_out;

    short* Qb  = (short*)d_ws;                // 16384*64 bf16 (pre-scaled)
    short* Ks  = Qb + (size_t)NROWS * 64;     // A-frag-major K
    short* Vs  = Ks + (size_t)NROWS * 64;     // B-frag-major V
    short* Wt2 = Vs + (size_t)NROWS * 64;     // 32*12*64*8 bf16 (frag-major)

    wprep_kernel<<<32, 256, 0, stream>>>(Wq, Wk, Wv, Wt2);
    qkv_kernel<<<NROWS / 32, 256, 0, stream>>>(x, cosp, sinp, Wt2, Qb, Ks, Vs);
    attn_kernel<<<dim3(128, 4), 256, 0, stream>>>(Qb, Ks, Vs, out);
}